// Round 14
// baseline (419.748 us; speedup 1.0000x reference)
//
#include <hip/hip_runtime.h>
#include <hip/hip_bf16.h>

// PermutationGenerator: B=8192, N=64, D=128, LATENT=256, TEMP=0.1, 20 Sinkhorn iters.
// d_in (ALL f32): [0] padded [B][64][128], [1] set_size int32 [B], [2] maskB (UNUSED),
//       [3] gumbel [B][64][64], [4] W1 [128][256], [5] b1 [256],
//       [6] W2 [256][64], [7] b2 [64]
// d_out f32: [0:8192] set_size, then permuted [B][64][128].
//
// R14: FUSED A+B (eliminates the 268MB P0 HBM round-trip; x re-read for GEMM3
// is L3-hot inside the same kernel). Concatenation of verified pieces:
//   R13-A: x staging (swz arena), GEMM1/GEMM2 (coalesced w1s/w2s), gn prefetch
//          (now row- AND col-gated), init -> p[i][n] fragment layout.
//   R8-B:  T14 x re-read (issued post-init, consumed post-sinkhorn), 20-iter
//          block-coop Sinkhorn (part @+32768, parity dbuf, 1 barrier/iter),
//          pth/xth staging, GEMM3, skewed outst, coalesced stores.
// LDS 34944 (arena 32768 + part 2176) -> 4 blocks/CU. NO launch bound (R13
// lesson: caps below acc pressure => scratch spill).

typedef _Float16 h16;
typedef h16 h8 __attribute__((ext_vector_type(8)));
typedef h16 h4 __attribute__((ext_vector_type(4)));
typedef __fp16 fp16x2 __attribute__((ext_vector_type(2)));
typedef float v4f __attribute__((ext_vector_type(4)));

template<int CTRL>
__device__ __forceinline__ float dppf(float x) {
  return __int_as_float(__builtin_amdgcn_update_dpp(
      0, __float_as_int(x), CTRL, 0xF, 0xF, true));
}
__device__ __forceinline__ float red16_sum(float x) {
  x += dppf<0xB1>(x);
  x += dppf<0x4E>(x);
  x += dppf<0x124>(x);
  x += dppf<0x128>(x);
  return x;
}
__device__ __forceinline__ float red16_max(float x) {
  x = fmaxf(x, dppf<0xB1>(x));
  x = fmaxf(x, dppf<0x4E>(x));
  x = fmaxf(x, dppf<0x124>(x));
  x = fmaxf(x, dppf<0x128>(x));
  return x;
}
__device__ __forceinline__ float frcp(float x) { return __builtin_amdgcn_rcpf(x); }
__device__ __forceinline__ h8 cvt8(v4f a, v4f b) {
  union { h8 v; fp16x2 p[4]; } u;
  u.p[0] = __builtin_amdgcn_cvt_pkrtz(a[0], a[1]);
  u.p[1] = __builtin_amdgcn_cvt_pkrtz(a[2], a[3]);
  u.p[2] = __builtin_amdgcn_cvt_pkrtz(b[0], b[1]);
  u.p[3] = __builtin_amdgcn_cvt_pkrtz(b[2], b[3]);
  return u.v;
}

// w1s[kk*8192 + col*32 + e] = W1[(kk*32+e)*256 + col]   (kk<4, col<256, e<32)
// w2s[kk*2048 + j*32 + e]   = W2[(kk*32+e)*64 + j]      (kk<8, j<64,  e<32)
__global__ __launch_bounds__(256) void prep_w(const float* __restrict__ W1,
                                              const float* __restrict__ W2,
                                              h16* __restrict__ w1s,
                                              h16* __restrict__ w2s) {
  int t = blockIdx.x * 256 + threadIdx.x;
  if (t < 128 * 256) {
    int row = t >> 8, col = t & 255;          // W1[row][col]
    int kk = row >> 5, e = row & 31;
    w1s[kk * 8192 + col * 32 + e] = (h16)W1[t];
  } else if (t < 128 * 256 + 256 * 64) {
    int t2 = t - 128 * 256;
    int row = t2 >> 6, j = t2 & 63;           // W2[row][j]
    int kk = row >> 5, e = row & 31;
    w2s[kk * 2048 + j * 32 + e] = (h16)W2[t2];
  }
}

// Runs LAST on the stream.
__global__ __launch_bounds__(256) void write_ss(const int* __restrict__ ssz,
                                                float* __restrict__ outp) {
  int b = blockIdx.x * 256 + threadIdx.x;
  if (b < 8192) outp[b] = (float)ssz[b];
}

// ================= Fused kernel: MLP + init + Sinkhorn + GEMM3 + store =======
// LDS: arena [0,32768): xh[64][128]swz -> hh[64][256]swz -> xth[128][72]@0 +
//      pth[64][72]@18432 -> outst f32[64][128]swk @0.   part f32 @32768 (2176B).
template<bool WSF>
__global__ __launch_bounds__(256) void permgen_fused(
    const float* __restrict__ xf,
    const int* __restrict__ ssz,
    const float* __restrict__ gn,
    const float* __restrict__ b1,
    const float* __restrict__ b2,
    const h16* __restrict__ w1s,   // coalesced layout
    const h16* __restrict__ w2s,
    const float* __restrict__ W1f,
    const float* __restrict__ W2f,
    float* __restrict__ outp) {
  __shared__ __align__(16) char smem[34944];
  h16* xth = (h16*)smem;
  h16* pth = (h16*)(smem + 18432);
  float* outst = (float*)smem;
  float* part = (float*)(smem + 32768);

  const int tid = threadIdx.x, b = blockIdx.x;
  const int w = tid >> 6, lane = tid & 63, g = lane >> 4, lc = lane & 15;
  const int k = ssz[b];
  const int sr = tid >> 2, sseg = tid & 3;

  {  // stage x -> f16 LDS xh [64][128] swizzled: byte = r*256 + c*2 ^ ((r&7)<<4)
    const float* src = xf + (size_t)b * 8192 + sr * 128 + sseg * 32;
#pragma unroll
    for (int v = 0; v < 4; ++v) {
      const int byte = (sr * 256 + (sseg * 32 + v * 8) * 2) ^ ((sr & 7) << 4);
      *(h8*)(smem + byte) =
          cvt8(*(const v4f*)(src + v * 8), *(const v4f*)(src + v * 8 + 4));
    }
  }
  float b1v[4], b2v[4];
#pragma unroll
  for (int n = 0; n < 4; ++n) b1v[n] = b1[w * 64 + n * 16 + lc];
#pragma unroll
  for (int n = 0; n < 4; ++n) b2v[n] = b2[n * 16 + lc];
  __syncthreads();

  // GEMM1: h = relu(x@W1+b1); wave w -> cols [64w,64w+64)
  v4f acc1[4][4];
#pragma unroll
  for (int m = 0; m < 4; ++m)
#pragma unroll
    for (int n = 0; n < 4; ++n) acc1[m][n] = (v4f){0.f, 0.f, 0.f, 0.f};
#pragma unroll
  for (int kk = 0; kk < 4; ++kk) {
    h8 av[4], bv[4];
#pragma unroll
    for (int m = 0; m < 4; ++m) {
      const int row = lc + 16 * m;
      const int byte = (row * 256 + (kk * 32 + 8 * g) * 2) ^ ((row & 7) << 4);
      av[m] = *(const h8*)(smem + byte);
    }
#pragma unroll
    for (int n = 0; n < 4; ++n) {
      if (WSF) {
        bv[n] = *(const h8*)&w1s[kk * 8192 + (w * 64 + n * 16 + lc) * 32 + 8 * g];
      } else {
        h8 t;
#pragma unroll
        for (int e = 0; e < 8; ++e)
          t[e] = (h16)W1f[(kk * 32 + 8 * g + e) * 256 + (w * 64 + n * 16 + lc)];
        bv[n] = t;
      }
    }
#pragma unroll
    for (int m = 0; m < 4; ++m)
#pragma unroll
      for (int n = 0; n < 4; ++n)
        acc1[m][n] = __builtin_amdgcn_mfma_f32_16x16x32_f16(av[m], bv[n], acc1[m][n], 0, 0, 0);
  }

  // gn prefetch in LOW-pressure window; row- AND col-gated (64B line = n-block)
  float gnr[4][4];
#pragma unroll
  for (int i = 0; i < 4; ++i)
#pragma unroll
    for (int n = 0; n < 4; ++n) gnr[i][n] = 0.0f;
  if (16 * w < k) {
    const float* gnb = gn + (size_t)b * 4096;
#pragma unroll
    for (int i = 0; i < 4; ++i)
#pragma unroll
      for (int n = 0; n < 4; ++n)
        if (16 * n < k)
          gnr[i][n] = gnb[(16 * w + 4 * g + i) * 64 + 16 * n + lc];
  }

  __syncthreads();   // xh dead; arena becomes hh
  // hh store: byte = row*512 + col*2 ^ ((row&7)<<4)
#pragma unroll
  for (int m = 0; m < 4; ++m)
#pragma unroll
    for (int n = 0; n < 4; ++n)
#pragma unroll
      for (int q = 0; q < 4; ++q) {
        const int row = 16 * m + 4 * g + q;
        const int col = w * 64 + 16 * n + lc;
        const int byte = (row * 512 + col * 2) ^ ((row & 7) << 4);
        *(h16*)(smem + byte) = (h16)fmaxf(acc1[m][n][q] + b1v[n], 0.0f);
      }
  __syncthreads();

  // GEMM2: net rows [16w,16w+16); thread owns rows 16w+4g+i, cols 16n+lc
  v4f acc2[4];
#pragma unroll
  for (int n = 0; n < 4; ++n) acc2[n] = (v4f){0.f, 0.f, 0.f, 0.f};
  {
    const int row2 = 16 * w + lc;
#pragma unroll
    for (int kk = 0; kk < 8; ++kk) {
      const int byte = (row2 * 512 + (kk * 32 + 8 * g) * 2) ^ ((row2 & 7) << 4);
      h8 av = *(const h8*)(smem + byte);
#pragma unroll
      for (int n = 0; n < 4; ++n) {
        h8 bv;
        if (WSF) {
          bv = *(const h8*)&w2s[kk * 2048 + (n * 16 + lc) * 32 + 8 * g];
        } else {
          h8 t;
#pragma unroll
          for (int e = 0; e < 8; ++e)
            t[e] = (h16)W2f[(kk * 32 + 8 * g + e) * 64 + (n * 16 + lc)];
          bv = t;
        }
        acc2[n] = __builtin_amdgcn_mfma_f32_16x16x32_f16(av, bv, acc2[n], 0, 0, 0);
      }
    }
  }

  // init: p = exp2((la - rowmax)*10*log2e), masked -> 0  (fragment layout:
  // thread (w,g,lc) elem (i,n) = P[16w+4g+i][16n+lc] — fed directly to sinkhorn)
  float p[4][4];
#pragma unroll
  for (int i = 0; i < 4; ++i)
#pragma unroll
    for (int n = 0; n < 4; ++n) p[i][n] = 0.0f;
  if (16 * w < k) {
#pragma unroll
    for (int i = 0; i < 4; ++i) {
      const int row = 16 * w + 4 * g + i;
      float la[4];
#pragma unroll
      for (int n = 0; n < 4; ++n) {
        const int col = 16 * n + lc;
        const bool valid = (row < k) && (col < k);
        const float v = acc2[n][i] + b2v[n] + gnr[i][n];
        la[n] = valid ? v : -1e30f;
      }
      float m_ = fmaxf(fmaxf(la[0], la[1]), fmaxf(la[2], la[3]));
      m_ = red16_max(m_);
#pragma unroll
      for (int n = 0; n < 4; ++n)
        p[i][n] = (la[n] > -1e29f) ? exp2f((la[n] - m_) * 14.4269504089f) : 0.0f;
    }
  }

  // T14: issue x re-read NOW (L3-hot; consumed at xth staging after sinkhorn)
  v4f xr[8];
  {
    const float* src = xf + (size_t)b * 8192 + sr * 128 + sseg * 32;
#pragma unroll
    for (int v = 0; v < 8; ++v) xr[v] = *(const v4f*)(src + v * 4);
  }

  // 20 Sinkhorn iterations (R8-B verbatim; part @+32768, parity dbuf,
  // 1 barrier/iter; zeros stay zero so no masking needed)
#pragma unroll 1
  for (int it = 0; it < 20; ++it) {
#pragma unroll
    for (int i = 0; i < 4; ++i) {  // row norm: DPP-only
      float s = (p[i][0] + p[i][1]) + (p[i][2] + p[i][3]);
      s = red16_sum(s);
      const float sc = frcp(s + 1e-30f);
#pragma unroll
      for (int n = 0; n < 4; ++n) p[i][n] *= sc;
    }
    float cp[4];
#pragma unroll
    for (int n = 0; n < 4; ++n) {  // col partials over this wave's 16 rows
      float c = (p[0][n] + p[1][n]) + (p[2][n] + p[3][n]);
      c += __shfl_xor(c, 16);
      c += __shfl_xor(c, 32);
      cp[n] = c;
    }
    if (lane < 16) {
#pragma unroll
      for (int n = 0; n < 4; ++n)
        part[((it & 1) * 4 + w) * 68 + 16 * n + lc] = cp[n];
    }
    __syncthreads();
#pragma unroll
    for (int n = 0; n < 4; ++n) {
      float cs = 0.0f;
#pragma unroll
      for (int pw = 0; pw < 4; ++pw)
        cs += part[((it & 1) * 4 + pw) * 68 + 16 * n + lc];
      const float sc = frcp(cs + 1e-30f);
#pragma unroll
      for (int i = 0; i < 4; ++i) p[i][n] *= sc;
    }
  }

  // stage P^T and x^T into arena (hh dead — 20 sinkhorn barriers passed)
#pragma unroll
  for (int n = 0; n < 4; ++n) {
    h4 t;
#pragma unroll
    for (int i = 0; i < 4; ++i) t[i] = (h16)p[i][n];
    *(h4*)&pth[(16 * n + lc) * 72 + 16 * w + 4 * g] = t;  // P^T[col j][rows i..]
  }
#pragma unroll
  for (int v = 0; v < 4; ++v)
#pragma unroll
    for (int e = 0; e < 8; ++e) {
      const float xv = (e < 4) ? xr[2 * v][e] : xr[2 * v + 1][e - 4];
      xth[(sseg * 32 + v * 8 + e) * 72 + sr] = (h16)xv;  // x^T[f][i]
    }
  __syncthreads();

  // GEMM3 (full K=64): out = P^T @ x; wave w -> out cols [32w,32w+32)
  v4f acc3[4][2];
#pragma unroll
  for (int m = 0; m < 4; ++m)
#pragma unroll
    for (int nn = 0; nn < 2; ++nn) acc3[m][nn] = (v4f){0.f, 0.f, 0.f, 0.f};
#pragma unroll
  for (int kk = 0; kk < 2; ++kk) {
    h8 av[4], bv[2];
#pragma unroll
    for (int m = 0; m < 4; ++m)
      av[m] = *(h8*)&pth[(lc + 16 * m) * 72 + kk * 32 + 8 * g];
#pragma unroll
    for (int nn = 0; nn < 2; ++nn)
      bv[nn] = *(h8*)&xth[(32 * w + 16 * nn + lc) * 72 + kk * 32 + 8 * g];
#pragma unroll
    for (int m = 0; m < 4; ++m)
#pragma unroll
      for (int nn = 0; nn < 2; ++nn)
        acc3[m][nn] = __builtin_amdgcn_mfma_f32_16x16x32_f16(av[m], bv[nn], acc3[m][nn], 0, 0, 0);
  }
  __syncthreads();  // GEMM3 LDS reads done before outst overlays xth/pth

  // stage output skewed: outst[row][(col + 4*row) & 127]
#pragma unroll
  for (int m = 0; m < 4; ++m)
#pragma unroll
    for (int nn = 0; nn < 2; ++nn)
#pragma unroll
      for (int q = 0; q < 4; ++q) {
        const int row = 16 * m + 4 * g + q;
        const int col = 32 * w + 16 * nn + lc;
        outst[row * 128 + ((col + 4 * row) & 127)] = acc3[m][nn][q];
      }
  __syncthreads();

  {  // coalesced f32 store: 128B/thread
    float* dst = outp + 8192 + (size_t)b * 8192 + sr * 128 + sseg * 32;
#pragma unroll
    for (int v = 0; v < 8; ++v) {
      const int coff = (sseg * 32 + v * 4 + 4 * sr) & 127;
      *(v4f*)(dst + v * 4) = *(v4f*)&outst[sr * 128 + coff];
    }
  }
}

extern "C" void kernel_launch(void* const* d_in, const int* in_sizes, int n_in,
                              void* d_out, int out_size, void* d_ws, size_t ws_size,
                              hipStream_t stream) {
  const float* xf = (const float*)d_in[0];
  const int* ssz = (const int*)d_in[1];
  // d_in[2] = maskB: unused (recomputed from set_size)
  const float* gn = (const float*)d_in[3];
  const float* W1 = (const float*)d_in[4];
  const float* b1 = (const float*)d_in[5];
  const float* W2 = (const float*)d_in[6];
  const float* b2 = (const float*)d_in[7];
  float* outp = (float*)d_out;

  const size_t ws_need = (size_t)(128 * 256 + 256 * 64) * sizeof(h16);  // 98304 B
  const bool use_ws = (d_ws != nullptr) && (ws_size >= ws_need);

  if (use_ws) {
    h16* w1s = (h16*)d_ws;             // [4][256][32] f16
    h16* w2s = w1s + 128 * 256;        // [8][64][32]  f16
    prep_w<<<192, 256, 0, stream>>>(W1, W2, w1s, w2s);
    permgen_fused<true><<<8192, 256, 0, stream>>>(xf, ssz, gn, b1, b2, w1s, w2s,
                                                  W1, W2, outp);
  } else {
    permgen_fused<false><<<8192, 256, 0, stream>>>(xf, ssz, gn, b1, b2,
                                                   (const h16*)nullptr,
                                                   (const h16*)nullptr,
                                                   W1, W2, outp);
  }
  // set_size written LAST so nothing can clobber [0:8192).
  write_ss<<<32, 256, 0, stream>>>(ssz, outp);
}